// Round 6
// baseline (254.931 us; speedup 1.0000x reference)
//
#include <hip/hip_runtime.h>

// out = (sum_p cos(w_p * phi_p) + (N - C)) / N,  N = next pow2 >= C.
// Pure memory-bound reduction: 256 MiB read, 4 B write.
// R6: ONE-SHOT kernel — one thread per float4-pair, 32768 blocks. No
// grid-stride loop: every wave fires its 2 nt loads at wave start, so the
// memory queues stay saturated by block turnover (BabelStream-dot shape).
// R1-R5 loop-structured kernels plateaued at 2.6 (plain) / 3.8 TB/s (nt)
// regardless of depth & pattern -> issue-metering by the loop was the cap
// hypothesis. Harness restore/poison adds a fixed ~172 us to dur_us.

#define RTHREADS 256

typedef float v4f __attribute__((ext_vector_type(4)));

__global__ __launch_bounds__(RTHREADS) void qs_partial_kernel(
    const float* __restrict__ phi, const float* __restrict__ w,
    float* __restrict__ partials, int n4, int n) {
    const v4f* __restrict__ p4 = (const v4f*)phi;
    const v4f* __restrict__ w4 = (const v4f*)w;

    const int i = (int)blockIdx.x * RTHREADS + (int)threadIdx.x;

    float acc = 0.0f;
    if (i < n4) {
        v4f a = __builtin_nontemporal_load(p4 + i);
        v4f b = __builtin_nontemporal_load(w4 + i);
        acc = __cosf(a.x * b.x) + __cosf(a.y * b.y)
            + __cosf(a.z * b.z) + __cosf(a.w * b.w);
    }
    // scalar tail (n not divisible by 4) — single thread, tiny
    if (i == 0) {
        for (int j = n4 * 4; j < n; ++j) acc += __cosf(phi[j] * w[j]);
    }

    // wave-64 shuffle reduce
    #pragma unroll
    for (int off = 32; off > 0; off >>= 1)
        acc += __shfl_down(acc, off, 64);

    __shared__ float smem[RTHREADS / 64];
    int lane = threadIdx.x & 63;
    int wid  = threadIdx.x >> 6;
    if (lane == 0) smem[wid] = acc;
    __syncthreads();
    if (threadIdx.x == 0) {
        float t = 0.0f;
        #pragma unroll
        for (int k = 0; k < RTHREADS / 64; ++k) t += smem[k];
        partials[blockIdx.x] = t;
    }
}

__global__ __launch_bounds__(1024) void qs_final_kernel(
    const float* __restrict__ partials, float* __restrict__ out,
    int nb, float addend, float inv_n) {
    float acc = 0.0f;
    for (int i = threadIdx.x; i < nb; i += blockDim.x) acc += partials[i];

    #pragma unroll
    for (int off = 32; off > 0; off >>= 1)
        acc += __shfl_down(acc, off, 64);

    __shared__ float smem[1024 / 64];
    int lane = threadIdx.x & 63;
    int wid  = threadIdx.x >> 6;
    if (lane == 0) smem[wid] = acc;
    __syncthreads();
    if (threadIdx.x == 0) {
        float t = 0.0f;
        #pragma unroll
        for (int k = 0; k < 1024 / 64; ++k) t += smem[k];
        out[0] = (t + addend) * inv_n;  // overwrites poisoned d_out every call
    }
}

extern "C" void kernel_launch(void* const* d_in, const int* in_sizes, int n_in,
                              void* d_out, int out_size, void* d_ws, size_t ws_size,
                              hipStream_t stream) {
    const float* phi = (const float*)d_in[0];
    const float* w   = (const float*)d_in[1];
    float* out       = (float*)d_out;
    float* partials  = (float*)d_ws;

    int n  = in_sizes[0];
    int n4 = n >> 2;
    int nblocks = (n4 + RTHREADS - 1) / RTHREADS;   // 32768 for n = 2^25
    if (nblocks < 1) nblocks = 1;

    // N = 2^ceil(log2(n))
    long long N = 1;
    while (N < (long long)n) N <<= 1;
    float addend = (float)(N - (long long)n);
    float inv_n  = 1.0f / (float)N;

    qs_partial_kernel<<<nblocks, RTHREADS, 0, stream>>>(phi, w, partials, n4, n);
    qs_final_kernel<<<1, 1024, 0, stream>>>(partials, out, nblocks, addend, inv_n);
}